// Round 9
// baseline (243.105 us; speedup 1.0000x reference)
//
#include <hip/hip_runtime.h>

typedef __attribute__((ext_vector_type(8))) short short8;
typedef __attribute__((ext_vector_type(2))) float float2_t;
typedef __attribute__((ext_vector_type(4))) float float4_t;
typedef __attribute__((ext_vector_type(16))) float float16_t;

#define NB 32
#define NL 256
#define ND 128
#define OUT_PLANE (NB * ND * NL)   // elements per stacked output plane
#define XS 136                     // LDS row stride (bf16): conflict-free b128
#define BUFSZ (18 * XS)
#define FR_WORD 49152              // word-frag offset in ws (bf16 units)
#define CHRB 98304                 // bf16 chr_table offset in ws (bf16 units)
#define WS_ELEMS 114688            // total bf16 elements prepared in phase A
#define FLAG_BYTE_OFF (WS_ELEMS * 2)
#define GRID 1024                  // == 4 blocks/CU x 256 CU: all co-resident

__device__ inline unsigned short f2bf(float f) {
    union { float f; unsigned int i; } c;
    c.f = f;
    unsigned int r = c.i + 0x7FFFu + ((c.i >> 16) & 1u);  // RN-even
    return (unsigned short)(r >> 16);
}

// ---------------------------------------------------------------------------
// Single merged kernel, grid = 1024 blocks x 128 thr (2 waves).
// Phase A: frag prep — 112 ws elements per block:
//  [0..49151]      char B-frags for 32x32x16 (frag[s][nt][lane][j], s=0..23)
//  [49152..98303]  word B-frags for 16x16x32 (R6 layout)
//  [98304..114687] chr_table converted to bf16
// Then a device-scope arrive-and-spin barrier (flag in ws, memset to 0 by
// host each call; grid == co-resident capacity so spin cannot deadlock).
// Phase B: char path (all blocks, 8 words as 4 dual-word 32x32x16 pairs).
// Phase C: word path (blocks 0..511, one 16-l tile each, 16x16x32).
// ---------------------------------------------------------------------------
__global__ __launch_bounds__(128, 2) void conv_all(
    const int* __restrict__ wv, const int* __restrict__ wic,
    const float* __restrict__ wordT, const float* __restrict__ chrT,
    const float* __restrict__ Wc, const float* __restrict__ Ww,
    const float* __restrict__ biasC, const float* __restrict__ biasW,
    unsigned short* __restrict__ wsp, unsigned int* __restrict__ flag,
    float* __restrict__ out) {
    __shared__ unsigned short X[4][BUFSZ];
    const int tid  = threadIdx.x;
    const int wave = tid >> 6, lane = tid & 63;
    const int bid = blockIdx.x;

    // ---------------- Phase A: fragment prep (112 elems/block) ------------
    if (tid < 112) {
        int i = bid * 112 + tid;                       // 0..114687
        unsigned short val;
        if (i < FR_WORD) {                             // char 32x32 frags
            int j    = i & 7;
            int ln   = (i >> 3) & 63;
            int nt   = (i >> 9) & 3;
            int s    = i >> 11;                        // 0..23
            int dout = nt * 32 + (ln & 31);
            int kk   = s * 16 + ((ln >> 5) & 1) * 8 + j;
            int t    = kk >> 7;
            int d    = kk & 127;
            val = f2bf(Wc[(dout * 128 + d) * 3 + t]);
        } else if (i < CHRB) {                         // word 16x16 frags
            int ii = i - FR_WORD;
            int j    = ii & 7;
            int ln   = (ii >> 3) & 63;
            int nt   = (ii >> 9) & 7;
            int s    = ii >> 12;
            int dout = nt * 16 + (ln & 15);
            int t    = s >> 2;
            int k    = (s & 3) * 32 + ((ln >> 4) & 3) * 8 + j;
            val = f2bf(Ww[(dout * 128 + k) * 3 + t]);
        } else {
            val = f2bf(chrT[i - CHRB]);
        }
        wsp[i] = val;
    }
    // zero pad rows (c=-1 / c=16) of all 4 staging buffers while waiting
    for (int p = tid; p < XS; p += 128)
#pragma unroll
        for (int q = 0; q < 4; ++q) { X[q][p] = 0; X[q][17 * XS + p] = 0; }

    // ---------------- device-scope barrier --------------------------------
    __threadfence();       // flush this thread's phase-A stores to L2
    __syncthreads();       // all threads of block done
    if (tid == 0) {
        atomicAdd(flag, 1u);
        while (*(volatile unsigned int*)flag < (unsigned int)GRID)
            __builtin_amdgcn_s_sleep(8);
    }
    __syncthreads();
    __threadfence();       // order subsequent frag reads after the flag

    // ---------------- Phase B: char path (all blocks, 8 words) ------------
    {
        const unsigned short* chrB = wsp + CHRB;
        const int w0 = bid * 8;                // 8 consecutive words, same b
        const int b = w0 >> 8, l0 = w0 & 255;
        const int n32 = lane & 31;             // output col within ntile
        const int h   = (lane >> 5) & 1;       // k-half
        const int r15 = lane & 15;             // c-position within word
        const int wsel = (lane >> 4) & 1;      // 0: word j, 1: word j+1

        short8 bfrag[24][2];
#pragma unroll
        for (int s = 0; s < 24; ++s)
#pragma unroll
            for (int p = 0; p < 2; ++p)
                bfrag[s][p] = *(const short8*)(
                    wsp + (((s * 4 + wave * 2 + p) * 64 + lane) << 3));

        // staging map: 256 jobs/word = 16 rows x 16 chunks of 8 shorts (16B)
        const int ra = tid >> 4, sub = tid & 15;

        // prologue: stage words 0,1 into X[0],X[1]
#pragma unroll
        for (int q = 0; q < 2; ++q) {
            int j0 = wic[(w0 + q) * 16 + ra];
            int j1 = wic[(w0 + q) * 16 + ra + 8];
            short8 g0 = *(const short8*)(chrB + j0 * 128 + sub * 8);
            short8 g1 = *(const short8*)(chrB + j1 * 128 + sub * 8);
            *(short8*)&X[q][(ra + 1) * XS + sub * 8] = g0;
            *(short8*)&X[q][(ra + 9) * XS + sub * 8] = g1;
        }
        int iA0 = wic[(w0 + 2) * 16 + ra];       // word j+2 idx
        int iA1 = wic[(w0 + 2) * 16 + ra + 8];
        int iC0 = wic[(w0 + 3) * 16 + ra];       // word j+3 idx
        int iC1 = wic[(w0 + 3) * 16 + ra + 8];
        __syncthreads();

#pragma unroll
        for (int j = 0; j < 8; j += 2) {         // 4 dual-word pairs
            const unsigned short* abuf = X[(j + wsel) & 3];

            short8 g0, g1;
            if (j < 6) {   // staging loads for word j+2 under MFMA half 1
                g0 = *(const short8*)(chrB + iA0 * 128 + sub * 8);
                g1 = *(const short8*)(chrB + iA1 * 128 + sub * 8);
            }

            float16_t acc[2];
#pragma unroll
            for (int p = 0; p < 2; ++p)
#pragma unroll
                for (int e = 0; e < 16; ++e) acc[p][e] = 0.f;

#pragma unroll
            for (int s = 0; s < 12; ++s) {       // MFMA half 1
                short8 a = *(const short8*)&abuf[(r15 + (s >> 3)) * XS +
                                                 (s & 7) * 16 + h * 8];
#pragma unroll
                for (int p = 0; p < 2; ++p)
                    acc[p] = __builtin_amdgcn_mfma_f32_32x32x16_bf16(
                        a, bfrag[s][p], acc[p], 0, 0, 0);
            }

            short8 h0, h1;
            if (j < 6) {   // write word j+2; load word j+3 under half 2
                *(short8*)&X[(j + 2) & 3][(ra + 1) * XS + sub * 8] = g0;
                *(short8*)&X[(j + 2) & 3][(ra + 9) * XS + sub * 8] = g1;
                h0 = *(const short8*)(chrB + iC0 * 128 + sub * 8);
                h1 = *(const short8*)(chrB + iC1 * 128 + sub * 8);
                if (j < 4) {   // prefetch idx for words j+4, j+5
                    iA0 = wic[(w0 + j + 4) * 16 + ra];
                    iA1 = wic[(w0 + j + 4) * 16 + ra + 8];
                    iC0 = wic[(w0 + j + 5) * 16 + ra];
                    iC1 = wic[(w0 + j + 5) * 16 + ra + 8];
                }
            }

#pragma unroll
            for (int s = 12; s < 24; ++s) {      // MFMA half 2
                short8 a = *(const short8*)&abuf[(r15 + (s >> 3)) * XS +
                                                 (s & 7) * 16 + h * 8];
#pragma unroll
                for (int p = 0; p < 2; ++p)
                    acc[p] = __builtin_amdgcn_mfma_f32_32x32x16_bf16(
                        a, bfrag[s][p], acc[p], 0, 0, 0);
            }

            if (j < 6) {
                *(short8*)&X[(j + 3) & 3][(ra + 1) * XS + sub * 8] = h0;
                *(short8*)&X[(j + 3) & 3][(ra + 9) * XS + sub * 8] = h1;
            }

            // epilogue: rows = c (word0: regs 0..7, word1: regs 8..15);
            // col = lane&31; xor-32 merges the two k-half row groups.
#pragma unroll
            for (int p = 0; p < 2; ++p) {
                float v0 = acc[p][0], v1 = acc[p][8];
#pragma unroll
                for (int e = 1; e < 8; ++e) {
                    v0 = fmaxf(v0, acc[p][e]);
                    v1 = fmaxf(v1, acc[p][e + 8]);
                }
                v0 = fmaxf(v0, __shfl_xor(v0, 32, 64));
                v1 = fmaxf(v1, __shfl_xor(v1, 32, 64));
                int dout = wave * 64 + p * 32 + n32;
                if (lane < 32) {
                    float bc = biasC[dout];
                    float2_t st = {v0 + bc, v1 + bc};
                    *(float2_t*)&out[OUT_PLANE + b * (ND * NL) + dout * NL +
                                     l0 + j] = st;
                }
            }
            __syncthreads();  // protects next pair's buffer overwrites
        }
    }

    // ---------------- Phase C: word path (blocks 0..511) ------------------
    if (bid < 512) {
        const int m = lane & 15, quad = lane >> 4;
        const int b = bid >> 4, l0 = (bid & 15) << 4;
        short8 bfrag[12][4];
#pragma unroll
        for (int s = 0; s < 12; ++s)
#pragma unroll
            for (int p = 0; p < 4; ++p)
                bfrag[s][p] = *(const short8*)(
                    wsp + FR_WORD + (((s * 8 + wave * 4 + p) * 64 + lane) << 3));
        float bb[4];
#pragma unroll
        for (int p = 0; p < 4; ++p) bb[p] = biasW[wave * 64 + p * 16 + m];

#pragma unroll
        for (int i0 = 0; i0 < 2; ++i0) {   // 18 rows x 8 segs = 144 jobs
            int i = tid + i0 * 128;
            if (i < 144) {
                int rr = i >> 3, sg = i & 7;
                int l = l0 + rr - 1;
                int idx = (l >= 0 && l < NL) ? wv[b * NL + l] : 0;  // row0=0s
                const float4_t* src =
                    (const float4_t*)(wordT + idx * 128 + sg * 16);
                float4_t f0 = src[0], f1 = src[1], f2 = src[2], f3 = src[3];
                unsigned short t16[16];
                t16[0]=f2bf(f0.x); t16[1]=f2bf(f0.y); t16[2]=f2bf(f0.z); t16[3]=f2bf(f0.w);
                t16[4]=f2bf(f1.x); t16[5]=f2bf(f1.y); t16[6]=f2bf(f1.z); t16[7]=f2bf(f1.w);
                t16[8]=f2bf(f2.x); t16[9]=f2bf(f2.y); t16[10]=f2bf(f2.z); t16[11]=f2bf(f2.w);
                t16[12]=f2bf(f3.x); t16[13]=f2bf(f3.y); t16[14]=f2bf(f3.z); t16[15]=f2bf(f3.w);
                *(short8*)&X[0][rr * XS + sg * 16]     = *(const short8*)&t16[0];
                *(short8*)&X[0][rr * XS + sg * 16 + 8] = *(const short8*)&t16[8];
            }
        }
        __syncthreads();

        float4_t acc[4];
#pragma unroll
        for (int p = 0; p < 4; ++p) acc[p] = (float4_t){0.f, 0.f, 0.f, 0.f};
#pragma unroll
        for (int s = 0; s < 12; ++s) {
            short8 a = *(const short8*)&X[0][(m + (s >> 2)) * XS +
                                            (s & 3) * 32 + quad * 8];
#pragma unroll
            for (int p = 0; p < 4; ++p)
                acc[p] = __builtin_amdgcn_mfma_f32_16x16x32_bf16(
                    a, bfrag[s][p], acc[p], 0, 0, 0);
        }

        // D[row = l_local = quad*4+reg][col = dout_local = m]; 4 l's per lane
        float* obase = out + b * (ND * NL) + l0 + quad * 4;
#pragma unroll
        for (int p = 0; p < 4; ++p) {
            int dout = wave * 64 + p * 16 + m;
            float4_t pk;
            pk.x = acc[p].x + bb[p];
            pk.y = acc[p].y + bb[p];
            pk.z = acc[p].z + bb[p];
            pk.w = acc[p].w + bb[p];
            *(float4_t*)&obase[dout * NL] = pk;
        }
    }
}

extern "C" void kernel_launch(void* const* d_in, const int* in_sizes, int n_in,
                              void* d_out, int out_size, void* d_ws,
                              size_t ws_size, hipStream_t stream) {
    const int* word_vector   = (const int*)d_in[0];
    const int* words_in_char = (const int*)d_in[1];
    const float* word_table  = (const float*)d_in[2];
    const float* chr_table   = (const float*)d_in[3];
    const float* conv_chr_w  = (const float*)d_in[4];
    const float* conv_chr_b  = (const float*)d_in[5];
    const float* conv_word_w = (const float*)d_in[6];
    const float* conv_word_b = (const float*)d_in[7];
    float* out            = (float*)d_out;
    unsigned short* wsp   = (unsigned short*)d_ws;
    unsigned int* flag    = (unsigned int*)((char*)d_ws + FLAG_BYTE_OFF);

    hipMemsetAsync(flag, 0, 4, stream);   // barrier counter = 0 (async: legal)
    conv_all<<<GRID, 128, 0, stream>>>(word_vector, words_in_char,
                                       word_table, chr_table,
                                       conv_chr_w, conv_word_w,
                                       conv_chr_b, conv_word_b,
                                       wsp, flag, out);
}

// Round 10
// 108.145 us; speedup vs baseline: 2.2479x; 2.2479x over previous
//
#include <hip/hip_runtime.h>

typedef __attribute__((ext_vector_type(8))) short short8;
typedef __attribute__((ext_vector_type(2))) float float2_t;
typedef __attribute__((ext_vector_type(4))) float float4_t;
typedef __attribute__((ext_vector_type(16))) float float16_t;

#define NB 32
#define NL 256
#define ND 128
#define OUT_PLANE (NB * ND * NL)   // elements per stacked output plane
#define XS 136                     // LDS row stride (bf16): conflict-free b128
#define BUFSZ (18 * XS)
#define FR_WORD 49152              // word-frag offset in ws (bf16 units)
#define CHRB 98304                 // bf16 chr_table offset in ws (bf16 units)

__device__ inline unsigned short f2bf(float f) {
    union { float f; unsigned int i; } c;
    c.f = f;
    unsigned int r = c.i + 0x7FFFu + ((c.i >> 16) & 1u);  // RN-even
    return (unsigned short)(r >> 16);
}

// ---------------------------------------------------------------------------
// ws prep (4 elems/thread, 112 blocks):
//  [0..49151]      char B-frags for 32x32x16: frag[s][nt][lane][j], s=0..23,
//                  nt=0..3. B[kk][n]: n=lane&31, kk=s*16+(lane>>5)*8+j;
//                  t=kk>>7, d=kk&127; value = Wc[dout][d][t].
//  [49152..98303]  word B-frags for 16x16x32 (R6 layout).
//  [98304..114687] chr_table converted to bf16 (row 0 stays all-zero).
// ---------------------------------------------------------------------------
__global__ void make_frags(const float* __restrict__ Wc,
                           const float* __restrict__ Ww,
                           const float* __restrict__ chrT,
                           unsigned short* __restrict__ out) {
#pragma unroll
    for (int q = 0; q < 4; ++q) {
        int i = blockIdx.x * 1024 + q * 256 + threadIdx.x;  // 0..114687
        unsigned short val;
        if (i < FR_WORD) {                                 // char 32x32 frags
            int j    = i & 7;
            int lane = (i >> 3) & 63;
            int nt   = (i >> 9) & 3;
            int s    = i >> 11;                            // 0..23
            int dout = nt * 32 + (lane & 31);
            int kk   = s * 16 + ((lane >> 5) & 1) * 8 + j;
            int t    = kk >> 7;
            int d    = kk & 127;
            val = f2bf(Wc[(dout * 128 + d) * 3 + t]);
        } else if (i < CHRB) {                             // word 16x16 frags
            int ii = i - FR_WORD;
            int j    = ii & 7;
            int lane = (ii >> 3) & 63;
            int nt   = (ii >> 9) & 7;
            int s    = ii >> 12;
            int dout = nt * 16 + (lane & 15);
            int t    = s >> 2;
            int k    = (s & 3) * 32 + ((lane >> 4) & 3) * 8 + j;
            val = f2bf(Ww[(dout * 128 + k) * 3 + t]);
        } else {
            val = f2bf(chrT[i - CHRB]);
        }
        out[i] = val;
    }
}

// ---------------------------------------------------------------------------
// Merged conv kernel, grid = 1024 = exactly one dispatch round at 4 blk/CU.
// Blocks 0..511: word path (16x16x32, 16 l per block).
// Blocks 512..1023: char path, 16 words as 8 dual-word 32x32x16 pairs
// (word0 = A rows 0..15 via lanes 0..15/32..47, word1 via lanes 16..31/48..63).
// 4 rotating LDS buffers, one barrier per pair; staging for words j+2/j+3
// issued under the two MFMA half-blocks. 128 thr = 2 waves.
// ---------------------------------------------------------------------------
__global__ __launch_bounds__(128, 2) void conv_kernel(
    const int* __restrict__ wv, const int* __restrict__ wic,
    const float* __restrict__ wordT,
    const unsigned short* __restrict__ ws,
    const float* __restrict__ biasC, const float* __restrict__ biasW,
    float* __restrict__ out) {
    __shared__ unsigned short X[4][BUFSZ];
    const int tid  = threadIdx.x;
    const int wave = tid >> 6, lane = tid & 63;
    const int bid = blockIdx.x;

    if (bid >= 512) {
        // ------------------------- char path -------------------------------
        const unsigned short* chrB = ws + CHRB;
        const int w0 = (bid - 512) * 16;       // 16 consecutive words, same b
        const int b = w0 >> 8, l0 = w0 & 255;
        const int n32 = lane & 31;             // output col within ntile
        const int h   = (lane >> 5) & 1;       // k-half
        const int r15 = lane & 15;             // c-position within word
        const int wsel = (lane >> 4) & 1;      // 0: word j, 1: word j+1

        short8 bfrag[24][2];
#pragma unroll
        for (int s = 0; s < 24; ++s)
#pragma unroll
            for (int p = 0; p < 2; ++p)
                bfrag[s][p] = *(const short8*)(
                    ws + (((s * 4 + wave * 2 + p) * 64 + lane) << 3));
        float bc[2];
#pragma unroll
        for (int p = 0; p < 2; ++p) bc[p] = biasC[wave * 64 + p * 32 + n32];

        // zero pad rows (c=-1 and c=16) in all 4 buffers; never overwritten
        for (int p = tid; p < XS; p += 128)
#pragma unroll
            for (int q = 0; q < 4; ++q) { X[q][p] = 0; X[q][17 * XS + p] = 0; }

        // staging map: 256 jobs/word = 16 rows x 16 chunks of 8 shorts (16B);
        // thread stages rows ra, ra+8 at chunk sub
        const int ra = tid >> 4, sub = tid & 15;

        // prologue: stage words 0,1 into X[0],X[1]
#pragma unroll
        for (int q = 0; q < 2; ++q) {
            int j0 = wic[(w0 + q) * 16 + ra];
            int j1 = wic[(w0 + q) * 16 + ra + 8];
            short8 g0 = *(const short8*)(chrB + j0 * 128 + sub * 8);
            short8 g1 = *(const short8*)(chrB + j1 * 128 + sub * 8);
            *(short8*)&X[q][(ra + 1) * XS + sub * 8] = g0;
            *(short8*)&X[q][(ra + 9) * XS + sub * 8] = g1;
        }
        int iA0 = wic[(w0 + 2) * 16 + ra];       // word j+2 idx
        int iA1 = wic[(w0 + 2) * 16 + ra + 8];
        int iC0 = wic[(w0 + 3) * 16 + ra];       // word j+3 idx
        int iC1 = wic[(w0 + 3) * 16 + ra + 8];
        __syncthreads();

        for (int j = 0; j < 16; j += 2) {        // 8 dual-word pairs
            const unsigned short* abuf = X[(j + wsel) & 3];

            short8 g0, g1;
            if (j < 14) {  // staging loads for word j+2 under MFMA half 1
                g0 = *(const short8*)(chrB + iA0 * 128 + sub * 8);
                g1 = *(const short8*)(chrB + iA1 * 128 + sub * 8);
            }

            float16_t acc[2];
#pragma unroll
            for (int p = 0; p < 2; ++p)
#pragma unroll
                for (int e = 0; e < 16; ++e) acc[p][e] = 0.f;

#pragma unroll
            for (int s = 0; s < 12; ++s) {       // MFMA half 1
                short8 a = *(const short8*)&abuf[(r15 + (s >> 3)) * XS +
                                                 (s & 7) * 16 + h * 8];
#pragma unroll
                for (int p = 0; p < 2; ++p)
                    acc[p] = __builtin_amdgcn_mfma_f32_32x32x16_bf16(
                        a, bfrag[s][p], acc[p], 0, 0, 0);
            }

            short8 h0, h1;
            if (j < 14) {  // write word j+2; load word j+3 under half 2
                *(short8*)&X[(j + 2) & 3][(ra + 1) * XS + sub * 8] = g0;
                *(short8*)&X[(j + 2) & 3][(ra + 9) * XS + sub * 8] = g1;
                h0 = *(const short8*)(chrB + iC0 * 128 + sub * 8);
                h1 = *(const short8*)(chrB + iC1 * 128 + sub * 8);
                if (j < 12) {  // prefetch idx for words j+4, j+5
                    iA0 = wic[(w0 + j + 4) * 16 + ra];
                    iA1 = wic[(w0 + j + 4) * 16 + ra + 8];
                    iC0 = wic[(w0 + j + 5) * 16 + ra];
                    iC1 = wic[(w0 + j + 5) * 16 + ra + 8];
                }
            }

#pragma unroll
            for (int s = 12; s < 24; ++s) {      // MFMA half 2
                short8 a = *(const short8*)&abuf[(r15 + (s >> 3)) * XS +
                                                 (s & 7) * 16 + h * 8];
#pragma unroll
                for (int p = 0; p < 2; ++p)
                    acc[p] = __builtin_amdgcn_mfma_f32_32x32x16_bf16(
                        a, bfrag[s][p], acc[p], 0, 0, 0);
            }

            if (j < 14) {
                *(short8*)&X[(j + 3) & 3][(ra + 1) * XS + sub * 8] = h0;
                *(short8*)&X[(j + 3) & 3][(ra + 9) * XS + sub * 8] = h1;
            }

            // epilogue: rows = c (word0: regs 0..7, word1: regs 8..15);
            // col = lane&31; xor-32 merges the two k-half row groups.
#pragma unroll
            for (int p = 0; p < 2; ++p) {
                float v0 = acc[p][0], v1 = acc[p][8];
#pragma unroll
                for (int e = 1; e < 8; ++e) {
                    v0 = fmaxf(v0, acc[p][e]);
                    v1 = fmaxf(v1, acc[p][e + 8]);
                }
                v0 = fmaxf(v0, __shfl_xor(v0, 32, 64));
                v1 = fmaxf(v1, __shfl_xor(v1, 32, 64));
                int dout = wave * 64 + p * 32 + n32;
                if (lane < 32) {
                    float2_t st = {v0 + bc[p], v1 + bc[p]};
                    *(float2_t*)&out[OUT_PLANE + b * (ND * NL) + dout * NL +
                                     l0 + j] = st;
                }
            }
            __syncthreads();  // protects next pair's buffer overwrites
        }
    } else {
        // ------------------------- word path (16x16x32) --------------------
        const int m = lane & 15, quad = lane >> 4;
        const int b = bid >> 4, l0 = (bid & 15) << 4;
        short8 bfrag[12][4];
#pragma unroll
        for (int s = 0; s < 12; ++s)
#pragma unroll
            for (int p = 0; p < 4; ++p)
                bfrag[s][p] = *(const short8*)(
                    ws + FR_WORD + (((s * 8 + wave * 4 + p) * 64 + lane) << 3));
        float bb[4];
#pragma unroll
        for (int p = 0; p < 4; ++p) bb[p] = biasW[wave * 64 + p * 16 + m];

#pragma unroll
        for (int i0 = 0; i0 < 2; ++i0) {   // 18 rows x 8 segs = 144 jobs
            int i = tid + i0 * 128;
            if (i < 144) {
                int rr = i >> 3, sg = i & 7;
                int l = l0 + rr - 1;
                int idx = (l >= 0 && l < NL) ? wv[b * NL + l] : 0;  // row0=0s
                const float4_t* src =
                    (const float4_t*)(wordT + idx * 128 + sg * 16);
                float4_t f0 = src[0], f1 = src[1], f2 = src[2], f3 = src[3];
                unsigned short t16[16];
                t16[0]=f2bf(f0.x); t16[1]=f2bf(f0.y); t16[2]=f2bf(f0.z); t16[3]=f2bf(f0.w);
                t16[4]=f2bf(f1.x); t16[5]=f2bf(f1.y); t16[6]=f2bf(f1.z); t16[7]=f2bf(f1.w);
                t16[8]=f2bf(f2.x); t16[9]=f2bf(f2.y); t16[10]=f2bf(f2.z); t16[11]=f2bf(f2.w);
                t16[12]=f2bf(f3.x); t16[13]=f2bf(f3.y); t16[14]=f2bf(f3.z); t16[15]=f2bf(f3.w);
                *(short8*)&X[0][rr * XS + sg * 16]     = *(const short8*)&t16[0];
                *(short8*)&X[0][rr * XS + sg * 16 + 8] = *(const short8*)&t16[8];
            }
        }
        __syncthreads();

        float4_t acc[4];
#pragma unroll
        for (int p = 0; p < 4; ++p) acc[p] = (float4_t){0.f, 0.f, 0.f, 0.f};
#pragma unroll
        for (int s = 0; s < 12; ++s) {
            short8 a = *(const short8*)&X[0][(m + (s >> 2)) * XS +
                                            (s & 3) * 32 + quad * 8];
#pragma unroll
            for (int p = 0; p < 4; ++p)
                acc[p] = __builtin_amdgcn_mfma_f32_16x16x32_bf16(
                    a, bfrag[s][p], acc[p], 0, 0, 0);
        }

        // D[row = l_local = quad*4+reg][col = dout_local = m]; 4 l's per lane
        float* obase = out + b * (ND * NL) + l0 + quad * 4;
#pragma unroll
        for (int p = 0; p < 4; ++p) {
            int dout = wave * 64 + p * 16 + m;
            float4_t pk;
            pk.x = acc[p].x + bb[p];
            pk.y = acc[p].y + bb[p];
            pk.z = acc[p].z + bb[p];
            pk.w = acc[p].w + bb[p];
            *(float4_t*)&obase[dout * NL] = pk;
        }
    }
}

extern "C" void kernel_launch(void* const* d_in, const int* in_sizes, int n_in,
                              void* d_out, int out_size, void* d_ws,
                              size_t ws_size, hipStream_t stream) {
    const int* word_vector   = (const int*)d_in[0];
    const int* words_in_char = (const int*)d_in[1];
    const float* word_table  = (const float*)d_in[2];
    const float* chr_table   = (const float*)d_in[3];
    const float* conv_chr_w  = (const float*)d_in[4];
    const float* conv_chr_b  = (const float*)d_in[5];
    const float* conv_word_w = (const float*)d_in[6];
    const float* conv_word_b = (const float*)d_in[7];
    float* out            = (float*)d_out;
    unsigned short* wsp   = (unsigned short*)d_ws;  // frags + bf16 chr_table

    make_frags<<<112, 256, 0, stream>>>(conv_chr_w, conv_word_w, chr_table, wsp);
    conv_kernel<<<1024, 128, 0, stream>>>(word_vector, words_in_char,
                                          word_table, wsp,
                                          conv_chr_b, conv_word_b, out);
}

// Round 11
// 103.420 us; speedup vs baseline: 2.3507x; 1.0457x over previous
//
#include <hip/hip_runtime.h>

typedef __attribute__((ext_vector_type(8))) short short8;
typedef __attribute__((ext_vector_type(2))) float float2_t;
typedef __attribute__((ext_vector_type(4))) float float4_t;
typedef __attribute__((ext_vector_type(16))) float float16_t;

#define NB 32
#define NL 256
#define ND 128
#define OUT_PLANE (NB * ND * NL)   // elements per stacked output plane
#define XS 136                     // LDS row stride (bf16): conflict-free b128
#define BUFSZ (18 * XS)
#define FR_WORD 49152              // word-frag offset in ws (bf16 units)
#define CHRB 98304                 // bf16 chr_table offset in ws (bf16 units)

__device__ inline unsigned short f2bf(float f) {
    union { float f; unsigned int i; } c;
    c.f = f;
    unsigned int r = c.i + 0x7FFFu + ((c.i >> 16) & 1u);  // RN-even
    return (unsigned short)(r >> 16);
}

// ---------------------------------------------------------------------------
// ws prep (4 elems/thread, 112 blocks):
//  [0..49151]      char B-frags for 32x32x16: frag[s][nt][lane][j], s=0..23,
//                  nt=0..3. B[kk][n]: n=lane&31, kk=s*16+(lane>>5)*8+j;
//                  t=kk>>7, d=kk&127; value = Wc[dout][d][t].
//  [49152..98303]  word B-frags for 16x16x32 (R6 layout).
//  [98304..114687] chr_table converted to bf16 (row 0 stays all-zero).
// ---------------------------------------------------------------------------
__global__ void make_frags(const float* __restrict__ Wc,
                           const float* __restrict__ Ww,
                           const float* __restrict__ chrT,
                           unsigned short* __restrict__ out) {
#pragma unroll
    for (int q = 0; q < 4; ++q) {
        int i = blockIdx.x * 1024 + q * 256 + threadIdx.x;  // 0..114687
        unsigned short val;
        if (i < FR_WORD) {                                 // char 32x32 frags
            int j    = i & 7;
            int lane = (i >> 3) & 63;
            int nt   = (i >> 9) & 3;
            int s    = i >> 11;                            // 0..23
            int dout = nt * 32 + (lane & 31);
            int kk   = s * 16 + ((lane >> 5) & 1) * 8 + j;
            int t    = kk >> 7;
            int d    = kk & 127;
            val = f2bf(Wc[(dout * 128 + d) * 3 + t]);
        } else if (i < CHRB) {                             // word 16x16 frags
            int ii = i - FR_WORD;
            int j    = ii & 7;
            int lane = (ii >> 3) & 63;
            int nt   = (ii >> 9) & 7;
            int s    = ii >> 12;
            int dout = nt * 16 + (lane & 15);
            int t    = s >> 2;
            int k    = (s & 3) * 32 + ((lane >> 4) & 3) * 8 + j;
            val = f2bf(Ww[(dout * 128 + k) * 3 + t]);
        } else {
            val = f2bf(chrT[i - CHRB]);
        }
        out[i] = val;
    }
}

// ---------------------------------------------------------------------------
// Merged conv kernel, grid = 1536. CHAR FIRST (longest blocks dispatch
// earliest): blocks 0..1023 char path (8 words as 4 dual-word 32x32x16
// pairs); blocks 1024..1535 word path (16x16x32, 16 l per block).
// 4 rotating LDS buffers, one barrier per pair; staging for words j+2/j+3
// issued under the two MFMA half-blocks. 128 thr = 2 waves.
// ---------------------------------------------------------------------------
__global__ __launch_bounds__(128, 2) void conv_kernel(
    const int* __restrict__ wv, const int* __restrict__ wic,
    const float* __restrict__ wordT,
    const unsigned short* __restrict__ ws,
    const float* __restrict__ biasC, const float* __restrict__ biasW,
    float* __restrict__ out) {
    __shared__ unsigned short X[4][BUFSZ];
    const int tid  = threadIdx.x;
    const int wave = tid >> 6, lane = tid & 63;
    const int bid = blockIdx.x;

    if (bid < 1024) {
        // ------------------------- char path -------------------------------
        const unsigned short* chrB = ws + CHRB;
        const int w0 = bid * 8;                // 8 consecutive words, same b
        const int b = w0 >> 8, l0 = w0 & 255;
        const int n32 = lane & 31;             // output col within ntile
        const int h   = (lane >> 5) & 1;       // k-half
        const int r15 = lane & 15;             // c-position within word
        const int wsel = (lane >> 4) & 1;      // 0: word j, 1: word j+1

        short8 bfrag[24][2];
#pragma unroll
        for (int s = 0; s < 24; ++s)
#pragma unroll
            for (int p = 0; p < 2; ++p)
                bfrag[s][p] = *(const short8*)(
                    ws + (((s * 4 + wave * 2 + p) * 64 + lane) << 3));
        float bc[2];
#pragma unroll
        for (int p = 0; p < 2; ++p) bc[p] = biasC[wave * 64 + p * 32 + n32];

        // zero pad rows (c=-1 and c=16) in all 4 buffers; never overwritten
        for (int p = tid; p < XS; p += 128)
#pragma unroll
            for (int q = 0; q < 4; ++q) { X[q][p] = 0; X[q][17 * XS + p] = 0; }

        // staging map: 256 jobs/word = 16 rows x 16 chunks of 8 shorts (16B);
        // thread stages rows ra, ra+8 at chunk sub
        const int ra = tid >> 4, sub = tid & 15;

        // prologue: stage words 0,1 into X[0],X[1]
#pragma unroll
        for (int q = 0; q < 2; ++q) {
            int j0 = wic[(w0 + q) * 16 + ra];
            int j1 = wic[(w0 + q) * 16 + ra + 8];
            short8 g0 = *(const short8*)(chrB + j0 * 128 + sub * 8);
            short8 g1 = *(const short8*)(chrB + j1 * 128 + sub * 8);
            *(short8*)&X[q][(ra + 1) * XS + sub * 8] = g0;
            *(short8*)&X[q][(ra + 9) * XS + sub * 8] = g1;
        }
        int iA0 = wic[(w0 + 2) * 16 + ra];       // word j+2 idx
        int iA1 = wic[(w0 + 2) * 16 + ra + 8];
        int iC0 = wic[(w0 + 3) * 16 + ra];       // word j+3 idx
        int iC1 = wic[(w0 + 3) * 16 + ra + 8];
        __syncthreads();

#pragma unroll
        for (int j = 0; j < 8; j += 2) {         // 4 dual-word pairs
            const unsigned short* abuf = X[(j + wsel) & 3];

            short8 g0, g1;
            if (j < 6) {   // staging loads for word j+2 under MFMA half 1
                g0 = *(const short8*)(chrB + iA0 * 128 + sub * 8);
                g1 = *(const short8*)(chrB + iA1 * 128 + sub * 8);
            }

            float16_t acc[2];
#pragma unroll
            for (int p = 0; p < 2; ++p)
#pragma unroll
                for (int e = 0; e < 16; ++e) acc[p][e] = 0.f;

#pragma unroll
            for (int s = 0; s < 12; ++s) {       // MFMA half 1
                short8 a = *(const short8*)&abuf[(r15 + (s >> 3)) * XS +
                                                 (s & 7) * 16 + h * 8];
#pragma unroll
                for (int p = 0; p < 2; ++p)
                    acc[p] = __builtin_amdgcn_mfma_f32_32x32x16_bf16(
                        a, bfrag[s][p], acc[p], 0, 0, 0);
            }

            short8 h0, h1;
            if (j < 6) {   // write word j+2; load word j+3 under half 2
                *(short8*)&X[(j + 2) & 3][(ra + 1) * XS + sub * 8] = g0;
                *(short8*)&X[(j + 2) & 3][(ra + 9) * XS + sub * 8] = g1;
                h0 = *(const short8*)(chrB + iC0 * 128 + sub * 8);
                h1 = *(const short8*)(chrB + iC1 * 128 + sub * 8);
                if (j < 4) {   // prefetch idx for words j+4, j+5
                    iA0 = wic[(w0 + j + 4) * 16 + ra];
                    iA1 = wic[(w0 + j + 4) * 16 + ra + 8];
                    iC0 = wic[(w0 + j + 5) * 16 + ra];
                    iC1 = wic[(w0 + j + 5) * 16 + ra + 8];
                }
            }

#pragma unroll
            for (int s = 12; s < 24; ++s) {      // MFMA half 2
                short8 a = *(const short8*)&abuf[(r15 + (s >> 3)) * XS +
                                                 (s & 7) * 16 + h * 8];
#pragma unroll
                for (int p = 0; p < 2; ++p)
                    acc[p] = __builtin_amdgcn_mfma_f32_32x32x16_bf16(
                        a, bfrag[s][p], acc[p], 0, 0, 0);
            }

            if (j < 6) {
                *(short8*)&X[(j + 3) & 3][(ra + 1) * XS + sub * 8] = h0;
                *(short8*)&X[(j + 3) & 3][(ra + 9) * XS + sub * 8] = h1;
            }

            // epilogue: rows = c (word0: regs 0..7, word1: regs 8..15);
            // col = lane&31; xor-32 merges the two k-half row groups.
#pragma unroll
            for (int p = 0; p < 2; ++p) {
                float v0 = acc[p][0], v1 = acc[p][8];
#pragma unroll
                for (int e = 1; e < 8; ++e) {
                    v0 = fmaxf(v0, acc[p][e]);
                    v1 = fmaxf(v1, acc[p][e + 8]);
                }
                v0 = fmaxf(v0, __shfl_xor(v0, 32, 64));
                v1 = fmaxf(v1, __shfl_xor(v1, 32, 64));
                int dout = wave * 64 + p * 32 + n32;
                if (lane < 32) {
                    float2_t st = {v0 + bc[p], v1 + bc[p]};
                    *(float2_t*)&out[OUT_PLANE + b * (ND * NL) + dout * NL +
                                     l0 + j] = st;
                }
            }
            __syncthreads();  // protects next pair's buffer overwrites
        }
    } else {
        // ------------------------- word path (16x16x32) --------------------
        const int wb = bid - 1024;
        const int m = lane & 15, quad = lane >> 4;
        const int b = wb >> 4, l0 = (wb & 15) << 4;
        short8 bfrag[12][4];
#pragma unroll
        for (int s = 0; s < 12; ++s)
#pragma unroll
            for (int p = 0; p < 4; ++p)
                bfrag[s][p] = *(const short8*)(
                    ws + FR_WORD + (((s * 8 + wave * 4 + p) * 64 + lane) << 3));
        float bb[4];
#pragma unroll
        for (int p = 0; p < 4; ++p) bb[p] = biasW[wave * 64 + p * 16 + m];

#pragma unroll
        for (int i0 = 0; i0 < 2; ++i0) {   // 18 rows x 8 segs = 144 jobs
            int i = tid + i0 * 128;
            if (i < 144) {
                int rr = i >> 3, sg = i & 7;
                int l = l0 + rr - 1;
                int idx = (l >= 0 && l < NL) ? wv[b * NL + l] : 0;  // row0=0s
                const float4_t* src =
                    (const float4_t*)(wordT + idx * 128 + sg * 16);
                float4_t f0 = src[0], f1 = src[1], f2 = src[2], f3 = src[3];
                unsigned short t16[16];
                t16[0]=f2bf(f0.x); t16[1]=f2bf(f0.y); t16[2]=f2bf(f0.z); t16[3]=f2bf(f0.w);
                t16[4]=f2bf(f1.x); t16[5]=f2bf(f1.y); t16[6]=f2bf(f1.z); t16[7]=f2bf(f1.w);
                t16[8]=f2bf(f2.x); t16[9]=f2bf(f2.y); t16[10]=f2bf(f2.z); t16[11]=f2bf(f2.w);
                t16[12]=f2bf(f3.x); t16[13]=f2bf(f3.y); t16[14]=f2bf(f3.z); t16[15]=f2bf(f3.w);
                *(short8*)&X[0][rr * XS + sg * 16]     = *(const short8*)&t16[0];
                *(short8*)&X[0][rr * XS + sg * 16 + 8] = *(const short8*)&t16[8];
            }
        }
        __syncthreads();

        float4_t acc[4];
#pragma unroll
        for (int p = 0; p < 4; ++p) acc[p] = (float4_t){0.f, 0.f, 0.f, 0.f};
#pragma unroll
        for (int s = 0; s < 12; ++s) {
            short8 a = *(const short8*)&X[0][(m + (s >> 2)) * XS +
                                            (s & 3) * 32 + quad * 8];
#pragma unroll
            for (int p = 0; p < 4; ++p)
                acc[p] = __builtin_amdgcn_mfma_f32_16x16x32_bf16(
                    a, bfrag[s][p], acc[p], 0, 0, 0);
        }

        // D[row = l_local = quad*4+reg][col = dout_local = m]; 4 l's per lane
        float* obase = out + b * (ND * NL) + l0 + quad * 4;
#pragma unroll
        for (int p = 0; p < 4; ++p) {
            int dout = wave * 64 + p * 16 + m;
            float4_t pk;
            pk.x = acc[p].x + bb[p];
            pk.y = acc[p].y + bb[p];
            pk.z = acc[p].z + bb[p];
            pk.w = acc[p].w + bb[p];
            *(float4_t*)&obase[dout * NL] = pk;
        }
    }
}

extern "C" void kernel_launch(void* const* d_in, const int* in_sizes, int n_in,
                              void* d_out, int out_size, void* d_ws,
                              size_t ws_size, hipStream_t stream) {
    const int* word_vector   = (const int*)d_in[0];
    const int* words_in_char = (const int*)d_in[1];
    const float* word_table  = (const float*)d_in[2];
    const float* chr_table   = (const float*)d_in[3];
    const float* conv_chr_w  = (const float*)d_in[4];
    const float* conv_chr_b  = (const float*)d_in[5];
    const float* conv_word_w = (const float*)d_in[6];
    const float* conv_word_b = (const float*)d_in[7];
    float* out            = (float*)d_out;
    unsigned short* wsp   = (unsigned short*)d_ws;  // frags + bf16 chr_table

    make_frags<<<112, 256, 0, stream>>>(conv_chr_w, conv_word_w, chr_table, wsp);
    conv_kernel<<<1536, 128, 0, stream>>>(word_vector, words_in_char,
                                          word_table, wsp,
                                          conv_chr_b, conv_word_b, out);
}